// Round 10
// baseline (25990.991 us; speedup 1.0000x reference)
//
#include <hip/hip_runtime.h>
#include <hip/hip_bf16.h>

#define TSTEPS 4096
#define XD 256
#define HD 2048
#define YD 256
#define KD 2304   // XD + HD
#define NWG 256
#define NT 512

// ---- LDS layout (bytes) ----
#define WU_OFF 0
#define WR_OFF (8*KD*2)              // 36864
#define WC_OFF (16*KD*2)             // 73728
#define WY_OFF (24*KD*2)             // 110592
#define HBUF_OFF (WY_OFF + HD*4)     // 118784  h_{t-1} (2048 f)
#define ZBUF_OFF (HBUF_OFF + HD*4)   // 126976  z = r*h  (2048 f)
#define RED_OFF (ZBUF_OFF + HD*4)    // 135168  yp[8..15], bu[16..23], br[24..31], bc[32..39], by[40]
#define LDS_BYTES (RED_OFF + 256)    // 135424

// ---- workspace ----
// R2 topology (6-leg relay, proven 21.2ms/correct) with CHEAPER LEGS:
//  - flags PACKED 4B/WG (8 lines total): hub = ONE wave gang-polling via
//    dwordx4 + __all vote (poll traffic 255 lines/iter -> 8, coalesced;
//    flag write-back 256 lines -> 8). R2's FETCH=567MB (138KB/step) was
//    poll self-traffic; this is the fix.
//  - go slots 32B apart (16 lines), hub wave stores all 64 in one shot.
//  - pipelined polls (2 outstanding) halve detect granularity on all
//    4 detect legs. No topology change; producer/consumer roles as R2.
#define HFLAGS_U32 0                 // 256 u32 packed  (bytes 0..1023)
#define ZFLAGS_U32 512               // 256 u32 packed  (bytes 2048..3071)
#define HGO_U32    1024              // 64 slots x 8 u32 apart (bytes 4096..6143)
#define ZGO_U32    1536              // (bytes 6144..8191)
#define WS_ZERO_BYTES 8192
#define HB0_OFF 8192                 // h exchange buffers (8 KB each, packed)
#define HB1_OFF 16384
#define RB0_OFF 24576                // z exchange buffers
#define RB1_OFF 32768

__device__ __forceinline__ float bflo(unsigned u){ return __uint_as_float(u << 16); }
__device__ __forceinline__ float bfhi(unsigned u){ return __uint_as_float(u & 0xffff0000u); }
__device__ __forceinline__ unsigned short f2bf(float f){
  unsigned b = __float_as_uint(f);
  b += 0x7fffu + ((b >> 16) & 1u);   // RTNE (inputs finite)
  return (unsigned short)(b >> 16);
}
__device__ __forceinline__ float sigmoidf_(float x){ return 1.0f / (1.0f + __expf(-x)); }

__device__ __forceinline__ void gst32f(float* p, float v){
  __hip_atomic_store(p, v, __ATOMIC_RELAXED, __HIP_MEMORY_SCOPE_AGENT);
}
__device__ __forceinline__ void flagst(unsigned* p, unsigned v){
  __hip_atomic_store(p, v, __ATOMIC_RELAXED, __HIP_MEMORY_SCOPE_AGENT);
}

// Pipelined go-poll: 2 loads in flight -> ~RTT/2 detect granularity.
// Compile-safe: "=v" outputs only (no tied "+v" — R3 lesson), standalone
// waitcnt + sched_barrier(0) fence (rule #18), scalar keep-alives.
__device__ __forceinline__ void spinflag2(const unsigned* p, unsigned epoch, long* budget){
  unsigned a, b;
  asm volatile("global_load_dword %0, %1, off sc1" : "=v"(a) : "v"(p) : "memory");
  asm volatile("global_load_dword %0, %1, off sc1" : "=v"(b) : "v"(p) : "memory");
  for (;;) {
    asm volatile("s_waitcnt vmcnt(1)" ::: "memory");
    __builtin_amdgcn_sched_barrier(0);
    if (a >= epoch) break;
    asm volatile("global_load_dword %0, %1, off sc1" : "=v"(a) : "v"(p) : "memory");
    asm volatile("s_waitcnt vmcnt(1)" ::: "memory");
    __builtin_amdgcn_sched_barrier(0);
    if (b >= epoch) break;
    asm volatile("global_load_dword %0, %1, off sc1" : "=v"(b) : "v"(p) : "memory");
    if ((*budget -= 2) < 0) break;   // anti-hang
    __builtin_amdgcn_s_sleep(1);
  }
  asm volatile("s_waitcnt vmcnt(0)" ::: "memory");
  asm volatile("" :: "v"(a), "v"(b));  // keep regs live past drain
}

// Hub gang-poll: ONE wave covers all 256 packed flags (lane i -> flags
// [4i..4i+4) via dwordx4), __all vote, pipelined 2-deep. Bit patterns
// compared as u32 (floats only carry them through VGPRs).
__device__ __forceinline__ void gangpoll(const unsigned* flags, unsigned epoch,
                                         int l6, long* budget){
  const float4* p = (const float4*)flags + l6;
  float4 A, B;
  asm volatile("global_load_dwordx4 %0, %1, off sc1" : "=v"(A) : "v"(p) : "memory");
  asm volatile("global_load_dwordx4 %0, %1, off sc1" : "=v"(B) : "v"(p) : "memory");
  for (;;) {
    asm volatile("s_waitcnt vmcnt(1)" ::: "memory");
    __builtin_amdgcn_sched_barrier(0);
    {
      int ok = (__float_as_uint(A.x) >= epoch) & (__float_as_uint(A.y) >= epoch)
             & (__float_as_uint(A.z) >= epoch) & (__float_as_uint(A.w) >= epoch);
      if (__all(ok)) break;
    }
    asm volatile("global_load_dwordx4 %0, %1, off sc1" : "=v"(A) : "v"(p) : "memory");
    asm volatile("s_waitcnt vmcnt(1)" ::: "memory");
    __builtin_amdgcn_sched_barrier(0);
    {
      int ok = (__float_as_uint(B.x) >= epoch) & (__float_as_uint(B.y) >= epoch)
             & (__float_as_uint(B.z) >= epoch) & (__float_as_uint(B.w) >= epoch);
      if (__all(ok)) break;
    }
    asm volatile("global_load_dwordx4 %0, %1, off sc1" : "=v"(B) : "v"(p) : "memory");
    if ((*budget -= 2) < 0) break;   // anti-hang
    __builtin_amdgcn_s_sleep(1);
  }
  asm volatile("s_waitcnt vmcnt(0)" ::: "memory");
  asm volatile("" :: "v"(A.x), "v"(A.y), "v"(A.z), "v"(A.w),
                     "v"(B.x), "v"(B.y), "v"(B.z), "v"(B.w));  // scalar keep-alives (no float4 inputs — R6)
}

// Certified data load (post-go; sc1 = LLC-serviced). R2-proven.
__device__ __forceinline__ float4 cohload16(const float4* p){
  float4 r;
  asm volatile("global_load_dwordx4 %0, %1, off sc1\n\t"
               "s_waitcnt vmcnt(0)"
               : "=v"(r) : "v"(p) : "memory");
  return r;
}
// Non-blocking issue (WG0 hides its data RTT under the window).
__device__ __forceinline__ float4 cohload16_issue(const float4* p){
  float4 r;
  asm volatile("global_load_dwordx4 %0, %1, off sc1"
               : "=v"(r) : "v"(p) : "memory");
  return r;
}

// Unrolled K-chunk of a column dot.
template<int I0, int I1, int STRIDE>
__device__ __forceinline__ void dotacc(const float* v, const unsigned short* wcol,
                                       int lane, float4& acc){
  #pragma unroll
  for (int i = I0; i < I1; ++i) {
    int k = 4 * (lane + STRIDE * i);
    float4 vv = *(const float4*)(v + k);
    uint2  wq = *(const uint2*)(wcol + k);
    acc.x = fmaf(vv.x, bflo(wq.x), acc.x);
    acc.y = fmaf(vv.y, bfhi(wq.x), acc.y);
    acc.z = fmaf(vv.z, bflo(wq.y), acc.z);
    acc.w = fmaf(vv.w, bfhi(wq.y), acc.w);
  }
}
__device__ __forceinline__ void xpart(const float4 xq, const unsigned short* wcol,
                                      int l6, float4& acc){
  uint2 wq = *(const uint2*)(wcol + 4*l6);
  acc.x = fmaf(xq.x, bflo(wq.x), acc.x);
  acc.y = fmaf(xq.y, bfhi(wq.x), acc.y);
  acc.z = fmaf(xq.z, bflo(wq.y), acc.z);
  acc.w = fmaf(xq.w, bfhi(wq.y), acc.w);
}
__device__ __forceinline__ float redux64(float4 a){
  float s = (a.x + a.y) + (a.z + a.w);
  s += __shfl_xor(s, 32); s += __shfl_xor(s, 16); s += __shfl_xor(s, 8);
  s += __shfl_xor(s, 4);  s += __shfl_xor(s, 2);  s += __shfl_xor(s, 1);
  return s;
}

extern "C" __global__ void __launch_bounds__(NT)
gru_persistent(const float* __restrict__ x,  const float* __restrict__ h0,
               const float* __restrict__ Wc, const float* __restrict__ Wu,
               const float* __restrict__ Wr, const float* __restrict__ bc,
               const float* __restrict__ bu, const float* __restrict__ br,
               const float* __restrict__ Wy, const float* __restrict__ by,
               float* __restrict__ out, unsigned* wsu)
{
  extern __shared__ char smem[];
  unsigned short* wuS = (unsigned short*)(smem + WU_OFF);
  unsigned short* wrS = (unsigned short*)(smem + WR_OFF);
  unsigned short* wcS = (unsigned short*)(smem + WC_OFF);
  float* wyS   = (float*)(smem + WY_OFF);
  float* hbufS = (float*)(smem + HBUF_OFF);
  float* zbufS = (float*)(smem + ZBUF_OFF);
  float* red   = (float*)(smem + RED_OFF);

  unsigned* hflags = wsu + HFLAGS_U32;   // packed: hflags[wg] at wsu[wg]
  unsigned* zflags = wsu + ZFLAGS_U32;
  unsigned* hgo    = wsu + HGO_U32;      // slot i at hgo + i*8 (32B apart)
  unsigned* zgo    = wsu + ZGO_U32;
  float* hb[2] = { (float*)((char*)wsu + HB0_OFF), (float*)((char*)wsu + HB1_OFF) };
  float* rb[2] = { (float*)((char*)wsu + RB0_OFF), (float*)((char*)wsu + RB1_OFF) };

  const int wg = blockIdx.x, tid = threadIdx.x;
  const int col0 = 8 * wg;

  // ---- one-time weight staging: WG j owns gate cols [8j,8j+8), y col j ----
  for (int idx = tid; idx < 8*KD; idx += NT) {
    int c = idx & 7, k = idx >> 3;
    size_t g = (size_t)k * HD + col0 + c;   // W is [KD, 2048] row-major
    wuS[c*KD + k] = f2bf(Wu[g]);
    wrS[c*KD + k] = f2bf(Wr[g]);
    wcS[c*KD + k] = f2bf(Wc[g]);
  }
  for (int k = tid; k < HD; k += NT) wyS[k] = Wy[(size_t)k * YD + wg];
  if (tid < 8) {
    red[16+tid] = bu[col0+tid];
    red[24+tid] = br[col0+tid];
    red[32+tid] = bc[col0+tid];
  }
  if (tid == 0) red[40] = by[wg];
  __syncthreads();

  long budget = 20000000;   // spin cap, then bail (no hang)

  const int w  = tid >> 6, l6 = tid & 63;          // wave / lane
  const int goline = ((wg & 7) << 3) + w;          // per-wave go slot (R2 map)
  const unsigned short* ucol = wuS + w * KD;
  const unsigned short* rcol = wrS + w * KD;
  const unsigned short* ccol = wcS + w * KD;

  float4 xq = ((const float4*)x)[l6];              // per-thread x chunk
  float ureg = 0.f;

  // hidden-window work: u gate (off critical path), y[t-1] partials,
  // x_{t+1} prefetch. Runs under the z-relay latency.
  auto window = [&](int t){
    float4 au = make_float4(0.f, 0.f, 0.f, 0.f);
    xpart(xq, ucol, l6, au);
    dotacc<1, 9, 64>(hbufS - XD, ucol, l6, au);
    ureg = sigmoidf_(redux64(au) + red[16 + w]);
    int k = 256 * w + 4 * l6;
    float4 hv4 = *(const float4*)(hbufS + k);
    float4 wy4 = *(const float4*)(wyS + k);
    float ys = fmaf(hv4.x, wy4.x, fmaf(hv4.y, wy4.y, fmaf(hv4.z, wy4.z, hv4.w * wy4.w)));
    ys += __shfl_xor(ys, 32); ys += __shfl_xor(ys, 16); ys += __shfl_xor(ys, 8);
    ys += __shfl_xor(ys, 4);  ys += __shfl_xor(ys, 2);  ys += __shfl_xor(ys, 1);
    if (l6 == 0) red[8 + w] = ys;
    if (t + 1 < TSTEPS) xq = ((const float4*)(x + (size_t)(t+1) * XD))[l6];
  };

  for (int t = 0; t < TSTEPS; ++t) {
    // r x-part (registers) — ahead of the h relay
    float4 a1 = make_float4(0.f, 0.f, 0.f, 0.f);
    xpart(xq, rcol, l6, a1);

    // ---- h_{t-1} exchange (epoch t) ----
    if (t == 0) {
      ((float4*)hbufS)[tid] = ((const float4*)h0)[tid];
    } else if (wg == 0) {
      if (w == 0) {                                  // hub = ONE wave, gang vote
        gangpoll(hflags, (unsigned)t, l6, &budget);
        flagst(hgo + l6*8, (unsigned)t);             // 64 go slots in one shot
      }
      __syncthreads();                               // release other hub waves
      ((float4*)hbufS)[tid] = cohload16((const float4*)hb[(t+1)&1] + tid);
    } else {
      if (l6 == 0) spinflag2(hgo + goline*8, (unsigned)t, &budget);
      ((float4*)hbufS)[tid] = cohload16((const float4*)hb[(t+1)&1] + tid);
    }
    __syncthreads();                                 // S1: h visible in LDS

    // ---- critical r-dot: wave w -> col col0+w, h part ----
    dotacc<1, 9, 64>(hbufS - XD, rcol, l6, a1);
    {
      float s = redux64(a1);
      if (l6 == 0)
        gst32f(rb[t&1] + col0 + w,
               sigmoidf_(s + red[24 + w]) * hbufS[col0 + w]);   // z = r*h
    }
    __syncthreads();                                 // drain z stores (vmcnt 0)
    if (tid == 0) flagst(zflags + wg, (unsigned)(t+1));

    // c x-part with x_t BEFORE window's prefetch overwrites xq
    float4 a2 = make_float4(0.f, 0.f, 0.f, 0.f);
    xpart(xq, ccol, l6, a2);

    // ---- z exchange (epoch t+1; window overlaps the wait / WG0's RTT) ----
    float4 rv;
    if (wg != 0) {
      window(t);
      if (l6 == 0) spinflag2(zgo + goline*8, (unsigned)(t+1), &budget);
      rv = cohload16((const float4*)rb[t&1] + tid);
    } else {
      if (w == 0) {
        gangpoll(zflags, (unsigned)(t+1), l6, &budget);
        flagst(zgo + l6*8, (unsigned)(t+1));
      }
      __syncthreads();
      rv = cohload16_issue((const float4*)rb[t&1] + tid);   // issue early
      window(t);                                            // hide RTT
      asm volatile("s_waitcnt vmcnt(0)" ::: "memory");
    }
    ((float4*)zbufS)[tid] = rv;
    __syncthreads();                                 // S2: z + u + y-partials

    // y[t-1] store: fire-and-forget, latency hidden under phase 2
    if (tid == 0 && t > 0) {
      float y = red[8]+red[9]+red[10]+red[11]+red[12]+red[13]+red[14]+red[15] + red[40];
      out[(size_t)(t-1) * YD + wg] = y;
    }

    // ---- phase 2: candidate (wave w -> col col0+w) ----
    dotacc<1, 9, 64>(zbufS - XD, ccol, l6, a2);
    {
      float s = redux64(a2);
      if (l6 == 0) {
        float cc = tanhf(s + red[32 + w]);
        float hp = hbufS[col0 + w];
        gst32f(hb[t&1] + col0 + w, cc * ureg + hp * (1.0f - ureg));  // h_t
      }
    }
    __syncthreads();                                 // drain h stores
    if (tid == 0) flagst(hflags + wg, (unsigned)(t+1));
  }

  // ---- epilogue: y[T-1] and h_fin (epoch TSTEPS) ----
  if (wg == 0) {
    if (w == 0) {
      gangpoll(hflags, (unsigned)TSTEPS, l6, &budget);
      flagst(hgo + l6*8, (unsigned)TSTEPS);
    }
    __syncthreads();
    ((float4*)hbufS)[tid] = cohload16((const float4*)hb[(TSTEPS-1)&1] + tid);
  } else {
    if (l6 == 0) spinflag2(hgo + goline*8, (unsigned)TSTEPS, &budget);
    ((float4*)hbufS)[tid] = cohload16((const float4*)hb[(TSTEPS-1)&1] + tid);
  }
  __syncthreads();
  {
    int k = 256 * w + 4 * l6;
    float4 hv4 = *(const float4*)(hbufS + k);
    float4 wy4 = *(const float4*)(wyS + k);
    float ys = fmaf(hv4.x, wy4.x, fmaf(hv4.y, wy4.y, fmaf(hv4.z, wy4.z, hv4.w * wy4.w)));
    ys += __shfl_xor(ys, 32); ys += __shfl_xor(ys, 16); ys += __shfl_xor(ys, 8);
    ys += __shfl_xor(ys, 4);  ys += __shfl_xor(ys, 2);  ys += __shfl_xor(ys, 1);
    if (l6 == 0) red[8 + w] = ys;
  }
  __syncthreads();
  if (tid == 0) {
    float y = red[8]+red[9]+red[10]+red[11]+red[12]+red[13]+red[14]+red[15] + red[40];
    out[(size_t)(TSTEPS-1) * YD + wg] = y;
  }
  if (tid < 8) out[(size_t)TSTEPS * YD + col0 + tid] = hbufS[col0 + tid];
}

extern "C" void kernel_launch(void* const* d_in, const int* in_sizes, int n_in,
                              void* d_out, int out_size, void* d_ws, size_t ws_size,
                              hipStream_t stream) {
  const float* x  = (const float*)d_in[0];
  const float* h0 = (const float*)d_in[1];
  const float* Wc = (const float*)d_in[2];
  const float* Wu = (const float*)d_in[3];
  const float* Wr = (const float*)d_in[4];
  const float* bc = (const float*)d_in[5];
  const float* bu = (const float*)d_in[6];
  const float* br = (const float*)d_in[7];
  const float* Wy = (const float*)d_in[8];
  const float* by = (const float*)d_in[9];
  float* out = (float*)d_out;
  unsigned* wsu = (unsigned*)d_ws;

  // >64 KB dynamic LDS on gfx950 (160 KB/CU). Idempotent; capture-safe.
  (void)hipFuncSetAttribute((const void*)gru_persistent,
                            hipFuncAttributeMaxDynamicSharedMemorySize, LDS_BYTES);
  (void)hipMemsetAsync(d_ws, 0, WS_ZERO_BYTES, stream);   // flags+go -> epoch 0
  gru_persistent<<<dim3(NWG), dim3(NT), LDS_BYTES, stream>>>(
      x, h0, Wc, Wu, Wr, bc, bu, br, Wy, by, out, wsu);
}